// Round 9
// baseline (209.516 us; speedup 1.0000x reference)
//
#include <hip/hip_runtime.h>
#include <hip/hip_bf16.h>

typedef __hip_bfloat16 bf16;
typedef unsigned short u16;
typedef unsigned int u32;
typedef __attribute__((ext_vector_type(8))) short short8;
typedef __attribute__((ext_vector_type(4))) float f32x4;

static constexpr float AVG_LOG_C = 2.8332133440562162f; // ln(17)
#define BCAP 2048   // staging capacity per 64-node bucket (avg ~1023)
#define CHUNK 8192  // edges per scatter block
#define PREP_TOTAL (8192 * 3 + 20480 * 2 + 64 * 6 + 1)

__device__ __forceinline__ u32 f2bf_bits(float f) {
    u32 u = __float_as_uint(f);
    return (u + 0x7fffu + ((u >> 16) & 1u)) >> 16;   // RNE to bf16 bits
}
__device__ __forceinline__ float bf2f(u16 b) {
    return __uint_as_float(((u32)b) << 16);
}

// ---------------------------------------------------------------- prep + bucket scatter (merged)
// blocks [0, scatB): chunked-reservation scatter into 64-node bucket staging.
// blocks [scatB, ...): local dtype-detect, then weight packing / fusion / bias cvt.
__global__ __launch_bounds__(1024) void prep_scatter_kernel(
    const int* __restrict__ srcs, const int* __restrict__ dsts,
    int* __restrict__ bcnt, u32* __restrict__ bstage, int e, int nb,
    const u32* __restrict__ xwords, int* __restrict__ flag,
    const void* __restrict__ W0r,  const void* __restrict__ b0r,
    const void* __restrict__ pre1r, const void* __restrict__ preb1r,
    const void* __restrict__ post1r, const void* __restrict__ postb1r,
    const void* __restrict__ lin1r, const void* __restrict__ linb1r,
    const void* __restrict__ pre2r, const void* __restrict__ preb2r,
    const void* __restrict__ post2r, const void* __restrict__ postb2r,
    const void* __restrict__ lin2r, const void* __restrict__ linb2r,
    const void* __restrict__ W2r,  const void* __restrict__ b2r,
    u16* __restrict__ W0p, u16* __restrict__ pre1p, u16* __restrict__ pre2p,
    u16* __restrict__ wf1p, u16* __restrict__ wf2p,
    float* __restrict__ bfo1, float* __restrict__ bfo2,
    float* __restrict__ preb1f, float* __restrict__ preb2f,
    float* __restrict__ b0f, float* __restrict__ W2f, float* __restrict__ b2f) {
    __shared__ int lhist[1024];
    __shared__ int lbase[1024];
    __shared__ int sflag;
    int tid = threadIdx.x;
    int scatB = (e + CHUNK - 1) / CHUNK;
    if ((int)blockIdx.x < scatB) {
        int cbase = blockIdx.x * CHUNK;
        for (int b = tid; b < nb; b += 1024) lhist[b] = 0;
        __syncthreads();
#pragma unroll
        for (int i = 0; i < CHUNK; i += 1024) {
            int e0 = cbase + i + tid;
            if (e0 < e) atomicAdd(&lhist[dsts[e0] >> 6], 1);
        }
        __syncthreads();
        for (int b = tid; b < nb; b += 1024) {
            int c = lhist[b];
            lbase[b] = c ? atomicAdd(&bcnt[b], c) : 0;
            lhist[b] = 0;   // becomes cursor
        }
        __syncthreads();
#pragma unroll
        for (int i = 0; i < CHUNK; i += 1024) {
            int e0 = cbase + i + tid;
            if (e0 < e) {
                int d = dsts[e0];
                int b = d >> 6;
                int pos = lbase[b] + atomicAdd(&lhist[b], 1);
                if (pos < BCAP)
                    bstage[(size_t)b * BCAP + pos] = (u32)srcs[e0] | ((u32)(d & 63) << 17);
            }
        }
        return;
    }
    // ------- local dtype detect (redundant per prep block; 8 KB read) -------
    if (tid < 64) {
        int good = 0;
        for (int i = tid; i < 2048; i += 64) {
            u32 lo = xwords[i] & 0xffffu;
            float v = __uint_as_float(lo << 16);
            float a = fabsf(v);
            if (v == 0.0f || (a >= 1e-3f && a <= 100.0f)) good++;
        }
        for (int off = 32; off; off >>= 1) good += __shfl_xor(good, off, 64);
        if (tid == 0) {
            sflag = (2 * good > 2048) ? 1 : 0;
            if ((int)blockIdx.x == scatB) *flag = sflag;   // publish for later kernels
        }
    }
    __syncthreads();
    bool isbf = sflag != 0;
    auto ld = [&](const void* p, int i) -> float {
        return isbf ? bf2f(((const u16*)p)[i]) : ((const float*)p)[i];
    };
    int idx = ((int)blockIdx.x - scatB) * 1024 + tid;
    if (idx < 8192) {   // W0p: mode0, K=128, NC=64
        int j = idx & 7, l = (idx >> 3) & 63, tt = idx >> 9;
        int c = tt & 3, s = tt >> 2;
        int kk = s * 32 + (l >> 4) * 8 + j;
        int col = c * 16 + (l & 15);
        W0p[idx] = (u16)f2bf_bits(ld(W0r, kk * 64 + col));
        return;
    }
    idx -= 8192;
    for (int which = 0; which < 2; ++which) {   // pre1p/pre2p: mode1
        if (idx < 8192) {
            const void* src = which ? pre2r : pre1r;
            u16* dst = which ? pre2p : pre1p;
            int j = idx & 7, l = (idx >> 3) & 63, tt = idx >> 9;
            int c = tt & 7, s = tt >> 3;
            int kk = s * 32 + (l >> 4) * 8 + j;
            int col = c * 16 + (l & 15);
            float v = (col < 64) ? ld(src, kk * 64 + col)
                                 : ld(src, (64 + kk) * 64 + (col - 64));
            dst[idx] = (u16)f2bf_bits(v);
            return;
        }
        idx -= 8192;
    }
    for (int which = 0; which < 2; ++which) {   // wf1p/wf2p: fused postW@linW
        if (idx < 20480) {
            const void* postW = which ? post2r : post1r;
            const void* linW  = which ? lin2r  : lin1r;
            u16* dst = which ? wf2p : wf1p;
            int j = idx & 7, l = (idx >> 3) & 63, tt = idx >> 9;
            int c = tt & 3, s = tt >> 2;
            int kk = s * 32 + (l >> 4) * 8 + j;
            int col = c * 16 + (l & 15);
            float a = 0.f;
            for (int k = 0; k < 64; ++k)
                a = fmaf(ld(postW, kk * 64 + k), ld(linW, k * 64 + col), a);
            dst[idx] = (u16)f2bf_bits(a);
            return;
        }
        idx -= 20480;
    }
    for (int which = 0; which < 2; ++which) {   // bfo = linb + postb @ linW
        if (idx < 64) {
            const void* postb = which ? postb2r : postb1r;
            const void* linW  = which ? lin2r : lin1r;
            const void* linb  = which ? linb2r : linb1r;
            float* dst = which ? bfo2 : bfo1;
            float a = ld(linb, idx);
            for (int k = 0; k < 64; ++k)
                a = fmaf(ld(postb, k), ld(linW, k * 64 + idx), a);
            dst[idx] = a;
            return;
        }
        idx -= 64;
    }
    if (idx < 64) { preb1f[idx] = ld(preb1r, idx); return; }
    idx -= 64;
    if (idx < 64) { preb2f[idx] = ld(preb2r, idx); return; }
    idx -= 64;
    if (idx < 64) { b0f[idx] = ld(b0r, idx); return; }
    idx -= 64;
    if (idx < 64) { W2f[idx] = ld(W2r, idx); return; }
    idx -= 64;
    if (idx < 1) { b2f[0] = ld(b2r, 0); }
}

// ---------------------------------------------------------------- gemm_x + fused pq1
__global__ __launch_bounds__(1024) void gemm_x_pq_kernel(
    const void* __restrict__ xraw, const u16* __restrict__ W0p,
    const float* __restrict__ b0f, const u16* __restrict__ pre1p,
    u16* __restrict__ hA, u16* __restrict__ PQ,
    const int* __restrict__ flag, int n) {
    __shared__ __align__(16) u16 xsh[64 * 136];
    __shared__ __align__(16) u16 hsh[64 * 72];
    int tid = threadIdx.x;
    int wave = __builtin_amdgcn_readfirstlane(tid >> 6);
    int lane = tid & 63;
    int blockbase = blockIdx.x * 64;
    bool isbf = (*flag) != 0;
    // phase 0: stage x tile (64x128 bf16)
    {
        int row = tid >> 4;
        int cg = (tid & 15) * 8;
        int grow = blockbase + row;
        short8 v = short8{0, 0, 0, 0, 0, 0, 0, 0};
        if (grow < n) {
            if (isbf) {
                v = *(const short8*)((const u16*)xraw + (size_t)grow * 128 + cg);
            } else {
                const float* xf = (const float*)xraw + (size_t)grow * 128 + cg;
                f32x4 a0 = *(const f32x4*)xf;
                f32x4 a1 = *(const f32x4*)(xf + 4);
#pragma unroll
                for (int j = 0; j < 4; ++j) {
                    v[j]     = (short)f2bf_bits(a0[j]);
                    v[4 + j] = (short)f2bf_bits(a1[j]);
                }
            }
        }
        *(short8*)&xsh[row * 136 + cg] = v;
    }
    __syncthreads();
    // phase 1: h tile (wave -> one 16x16 tile), K=128 (S=4)
    int rt = wave & 3, ct = wave >> 2;
    int arl = rt * 16 + (lane & 15);
    int koff = (lane >> 4) * 8;
    f32x4 acc = f32x4{0.f, 0.f, 0.f, 0.f};
#pragma unroll
    for (int s = 0; s < 4; ++s) {
        short8 a = *(const short8*)&xsh[arl * 136 + s * 32 + koff];
        short8 b = *(const short8*)(W0p + ((size_t)(s * 4 + ct) * 64 + lane) * 8);
        acc = __builtin_amdgcn_mfma_f32_16x16x32_bf16(a, b, acc, 0, 0, 0);
    }
    {
        int col = ct * 16 + (lane & 15);
        float bv = b0f[col];
        int r0l = rt * 16 + (lane >> 4) * 4;
#pragma unroll
        for (int r = 0; r < 4; ++r) {
            float v = acc[r] + bv;
            v = v > 0.f ? v : 0.2f * v;
            u16 bits = (u16)f2bf_bits(v);
            hsh[(r0l + r) * 72 + col] = bits;
            int grow = blockbase + r0l + r;
            if (grow < n) hA[(size_t)grow * 64 + col] = bits;
        }
    }
    __syncthreads();
    // phase 2: PQ = h @ pre1 (K=64, NCOL=128): 32 tiles, 2 per wave
#pragma unroll
    for (int half = 0; half < 2; ++half) {
        int tile = wave * 2 + half;
        int rt2 = tile & 3, ct2 = tile >> 2;
        int ar2 = rt2 * 16 + (lane & 15);
        f32x4 acc2 = f32x4{0.f, 0.f, 0.f, 0.f};
#pragma unroll
        for (int s = 0; s < 2; ++s) {
            short8 a = *(const short8*)&hsh[ar2 * 72 + s * 32 + koff];
            short8 b = *(const short8*)(pre1p + ((size_t)(s * 8 + ct2) * 64 + lane) * 8);
            acc2 = __builtin_amdgcn_mfma_f32_16x16x32_bf16(a, b, acc2, 0, 0, 0);
        }
        int col2 = ct2 * 16 + (lane & 15);
        int r02 = rt2 * 16 + (lane >> 4) * 4;
#pragma unroll
        for (int r = 0; r < 4; ++r) {
            int grow = blockbase + r02 + r;
            if (grow < n) PQ[(size_t)grow * 128 + col2] = (u16)f2bf_bits(acc2[r]);
        }
    }
}

// ---------------------------------------------------------------- fused local-CSR + agg + 320-GEMM
// block b <-> 64-node bucket b. Builds local CSR in LDS from bstage, gathers,
// then MFMA 320->64. PQin/PQout MUST be distinct buffers (cross-block race).
template<int FINAL>
__global__ __launch_bounds__(1024) void agg_gemm_kernel(
    const u16* __restrict__ PQ, const u16* __restrict__ h,
    const u32* __restrict__ bstage, const int* __restrict__ bcnt,
    const float* __restrict__ prebf, const u16* __restrict__ Wfp,
    const float* __restrict__ bfo, const u16* __restrict__ prenextp,
    u16* __restrict__ hout, u16* __restrict__ PQout,
    const float* __restrict__ W2f, const float* __restrict__ b2f,
    void* __restrict__ out, const int* __restrict__ flag, int n) {
    constexpr int PAD = 328;
    __shared__ __align__(16) u16 vsh[64 * PAD];   // 41 KB
    __shared__ __align__(16) u16 hsh[64 * 72];    // 9 KB
    __shared__ u32 lel[BCAP];                     // 8 KB local elist
    __shared__ int loff[64], lcnt[64], lcur[64];
    __shared__ float fsum[64];
    int tid = threadIdx.x;
    int wave = __builtin_amdgcn_readfirstlane(tid >> 6);
    int lane = tid & 63;
    int b = blockIdx.x;
    int blockbase = b * 64;
    float pbl = prebf[lane];
    if (tid < 64) { lcnt[tid] = 0; if (FINAL) fsum[tid] = 0.f; }
    __syncthreads();
    // phase 0a: local CSR from bucket staging
    int cb = min(bcnt[b], BCAP);
    const u32* st = bstage + (size_t)b * BCAP;
    for (int i = tid; i < cb; i += 1024) atomicAdd(&lcnt[st[i] >> 17], 1);
    __syncthreads();
    if (wave == 0) {
        int c = lcnt[lane];
        int s = c;
        for (int off = 1; off < 64; off <<= 1) {
            int t = __shfl_up(s, (unsigned)off, 64);
            if (lane >= off) s += t;
        }
        loff[lane] = s - c;
        lcur[lane] = s - c;
    }
    __syncthreads();
    for (int i = tid; i < cb; i += 1024) {
        u32 e = st[i];
        int pos = atomicAdd(&lcur[e >> 17], 1);
        lel[pos] = e & 0x1ffffu;
    }
    __syncthreads();
    // phase 0b: gather (4 nodes per wave), 16-deep load batches for MLP
    const u16* Qb = PQ + 64 + lane;
#pragma unroll
    for (int t = 0; t < 4; ++t) {
        int nl = wave * 4 + t;
        int node = blockbase + nl;
        u16* vrow = &vsh[nl * PAD];
        if (node < n) {
            int beg = loff[nl], end = beg + lcnt[nl];
            int cnt = end - beg;
            float s = 0.f, m = -3.4e38f;
            int e = beg;
            for (; e + 16 <= end; e += 16) {
                float q[16];
#pragma unroll
                for (int j = 0; j < 16; ++j)
                    q[j] = bf2f(Qb[(size_t)lel[e + j] * 128]);
                float sa = ((q[0] + q[1]) + (q[2] + q[3])) + ((q[4] + q[5]) + (q[6] + q[7]));
                float sb = ((q[8] + q[9]) + (q[10] + q[11])) + ((q[12] + q[13]) + (q[14] + q[15]));
                s += sa + sb;
                float ma = fmaxf(fmaxf(fmaxf(q[0], q[1]), fmaxf(q[2], q[3])),
                                 fmaxf(fmaxf(q[4], q[5]), fmaxf(q[6], q[7])));
                float mb = fmaxf(fmaxf(fmaxf(q[8], q[9]), fmaxf(q[10], q[11])),
                                 fmaxf(fmaxf(q[12], q[13]), fmaxf(q[14], q[15])));
                m = fmaxf(m, fmaxf(ma, mb));
            }
            for (; e + 4 <= end; e += 4) {
                float q0 = bf2f(Qb[(size_t)lel[e] * 128]);
                float q1 = bf2f(Qb[(size_t)lel[e + 1] * 128]);
                float q2 = bf2f(Qb[(size_t)lel[e + 2] * 128]);
                float q3 = bf2f(Qb[(size_t)lel[e + 3] * 128]);
                s += (q0 + q1) + (q2 + q3);
                m = fmaxf(fmaxf(m, fmaxf(q0, q1)), fmaxf(q2, q3));
            }
            for (; e < end; ++e) {
                float q = bf2f(Qb[(size_t)lel[e] * 128]);
                s += q;
                m = fmaxf(m, q);
            }
            float mean, mx, deg;
            if (cnt > 0) {
                deg = (float)cnt;
                float p = bf2f(PQ[(size_t)node * 128 + lane]) + pbl;
                mean = p + s / deg;
                mx = p + m;
            } else {
                deg = 1.f; mean = 0.f; mx = 0.f;
            }
            float att = AVG_LOG_C / logf(deg + 1.f);
            float lin = deg * (1.f / 16.f);
            vrow[lane]       = h[(size_t)node * 64 + lane];
            vrow[64 + lane]  = (u16)f2bf_bits(att * mean);
            vrow[128 + lane] = (u16)f2bf_bits(att * mx);
            vrow[192 + lane] = (u16)f2bf_bits(lin * mean);
            vrow[256 + lane] = (u16)f2bf_bits(lin * mx);
        } else {
            vrow[lane] = 0; vrow[64 + lane] = 0; vrow[128 + lane] = 0;
            vrow[192 + lane] = 0; vrow[256 + lane] = 0;
        }
    }
    __syncthreads();
    // phase 1: 320->64 GEMM, wave -> one 16x16 tile (S=10)
    int rt = wave & 3, ct = wave >> 2;
    int arl = rt * 16 + (lane & 15);
    int koff = (lane >> 4) * 8;
    f32x4 acc = f32x4{0.f, 0.f, 0.f, 0.f};
#pragma unroll
    for (int s = 0; s < 10; ++s) {
        short8 a = *(const short8*)&vsh[arl * PAD + s * 32 + koff];
        short8 b2 = *(const short8*)(Wfp + ((size_t)(s * 4 + ct) * 64 + lane) * 8);
        acc = __builtin_amdgcn_mfma_f32_16x16x32_bf16(a, b2, acc, 0, 0, 0);
    }
    int col = ct * 16 + (lane & 15);
    float bv = bfo[col];
    int r0l = rt * 16 + (lane >> 4) * 4;
    if constexpr (!FINAL) {
#pragma unroll
        for (int r = 0; r < 4; ++r) {
            float v = fmaxf(acc[r] + bv, 0.f);
            u16 bits = (u16)f2bf_bits(v);
            hsh[(r0l + r) * 72 + col] = bits;
            int grow = blockbase + r0l + r;
            if (grow < n) hout[(size_t)grow * 64 + col] = bits;
        }
        __syncthreads();
        // phase 2: PQout = hout @ prenext (K=64, NCOL=128)
#pragma unroll
        for (int half = 0; half < 2; ++half) {
            int tile = wave * 2 + half;
            int rt2 = tile & 3, ct2 = tile >> 2;
            int ar2 = rt2 * 16 + (lane & 15);
            f32x4 acc2 = f32x4{0.f, 0.f, 0.f, 0.f};
#pragma unroll
            for (int s = 0; s < 2; ++s) {
                short8 a = *(const short8*)&hsh[ar2 * 72 + s * 32 + koff];
                short8 b2 = *(const short8*)(prenextp + ((size_t)(s * 8 + ct2) * 64 + lane) * 8);
                acc2 = __builtin_amdgcn_mfma_f32_16x16x32_bf16(a, b2, acc2, 0, 0, 0);
            }
            int col2 = ct2 * 16 + (lane & 15);
            int r02 = rt2 * 16 + (lane >> 4) * 4;
#pragma unroll
            for (int r = 0; r < 4; ++r) {
                int grow = blockbase + r02 + r;
                if (grow < n) PQout[(size_t)grow * 128 + col2] = (u16)f2bf_bits(acc2[r]);
            }
        }
    } else {
        float w2 = W2f[col];
        float part[4];
#pragma unroll
        for (int r = 0; r < 4; ++r)
            part[r] = fmaxf(acc[r] + bv, 0.f) * w2;
#pragma unroll
        for (int r = 0; r < 4; ++r) {
            float v = part[r];
            v += __shfl_xor(v, 1, 64);
            v += __shfl_xor(v, 2, 64);
            v += __shfl_xor(v, 4, 64);
            v += __shfl_xor(v, 8, 64);
            if ((lane & 15) == 0) atomicAdd(&fsum[r0l + r], v);
        }
        __syncthreads();
        if (tid < 64) {
            int grow = blockbase + tid;
            if (grow < n) {
                float res = fsum[tid] + b2f[0];
                if (*flag) ((u16*)out)[grow] = (u16)f2bf_bits(res);
                else       ((float*)out)[grow] = res;
            }
        }
    }
}

// ---------------------------------------------------------------- launch
extern "C" void kernel_launch(void* const* d_in, const int* in_sizes, int n_in,
                              void* d_out, int out_size, void* d_ws, size_t ws_size,
                              hipStream_t stream) {
    const int N = in_sizes[0] / 128;
    const int E = in_sizes[2] / 2;
    const int nb = (N + 63) >> 6;
    const int* ei = (const int*)d_in[2];
    const int* esrc = ei;
    const int* edst = ei + E;

    char* w = (char*)d_ws;
    auto alloc = [&](size_t bytes) -> void* {
        void* p = (void*)w;
        w += (bytes + 255) & ~(size_t)255;
        return p;
    };
    int* flag    = (int*)alloc(4);
    int* bcnt    = (int*)alloc((size_t)nb * 4);
    u32* bstage  = (u32*)alloc((size_t)nb * BCAP * 4);
    // packed bf16 B-fragments
    u16* W0p     = (u16*)alloc(128 * 64 * 2);
    u16* pre1p   = (u16*)alloc(64 * 128 * 2);
    u16* pre2p   = (u16*)alloc(64 * 128 * 2);
    u16* wf1p    = (u16*)alloc(320 * 64 * 2);
    u16* wf2p    = (u16*)alloc(320 * 64 * 2);
    // f32 bias vectors
    float* bfo1  = (float*)alloc(64 * 4);
    float* bfo2  = (float*)alloc(64 * 4);
    float* preb1f= (float*)alloc(64 * 4);
    float* preb2f= (float*)alloc(64 * 4);
    float* b0f   = (float*)alloc(64 * 4);
    float* W2f   = (float*)alloc(64 * 4);
    float* b2f_  = (float*)alloc(4);
    // activations (bf16) — PQA/PQB double-buffered (cross-block race if shared)
    u16* hA      = (u16*)alloc((size_t)N * 64 * 2);
    u16* hB      = (u16*)alloc((size_t)N * 64 * 2);
    u16* PQA     = (u16*)alloc((size_t)N * 128 * 2);
    u16* PQB     = (u16*)alloc((size_t)N * 128 * 2);

    hipMemsetAsync(bcnt, 0, (size_t)nb * 4, stream);

    int scatB = (E + CHUNK - 1) / CHUNK;
    int prepB = (PREP_TOTAL + 1023) / 1024;
    prep_scatter_kernel<<<scatB + prepB, 1024, 0, stream>>>(
        esrc, edst, bcnt, bstage, E, nb,
        (const u32*)d_in[0], flag,
        d_in[3], d_in[4], d_in[5], d_in[6], d_in[7], d_in[8], d_in[9], d_in[10],
        d_in[11], d_in[12], d_in[13], d_in[14], d_in[15], d_in[16], d_in[17], d_in[18],
        W0p, pre1p, pre2p, wf1p, wf2p,
        bfo1, bfo2, preb1f, preb2f, b0f, W2f, b2f_);

    int gblocks = (N + 63) / 64;
    gemm_x_pq_kernel<<<gblocks, 1024, 0, stream>>>(
        d_in[0], W0p, b0f, pre1p, hA, PQA, flag, N);

    agg_gemm_kernel<0><<<gblocks, 1024, 0, stream>>>(
        PQA, hA, bstage, bcnt, preb1f, wf1p, bfo1, pre2p, hB, PQB,
        nullptr, nullptr, nullptr, flag, N);

    agg_gemm_kernel<1><<<gblocks, 1024, 0, stream>>>(
        PQB, hB, bstage, bcnt, preb2f, wf2p, bfo2, nullptr, nullptr, nullptr,
        W2f, b2f_, d_out, flag, N);
}